// Round 6
// baseline (513.003 us; speedup 1.0000x reference)
//
#include <hip/hip_runtime.h>
#include <hip/hip_bf16.h>

#define B_   32
#define T_   32
#define E_   32
#define SD   64
#define AD   32
#define HID  1024
#define EMB  1536
#define K2   3072   // 2*EMB
#define GMAX 4      // max batches per cat-group

typedef __attribute__((ext_vector_type(8))) short  bf16x8;
typedef __attribute__((ext_vector_type(8))) short  s16x8;
typedef __attribute__((ext_vector_type(4))) float  f32x4;

// round-to-nearest-even f32 -> bf16 bits
__device__ __forceinline__ unsigned short f2bf(float f) {
    unsigned u = __builtin_bit_cast(unsigned, f);
    u = u + 0x7fffu + ((u >> 16) & 1u);
    return (unsigned short)(u >> 16);
}

__device__ __forceinline__ float swishf(float y) {
    return y / (1.f + expf(-y));
}

// ---------------------------------------------------------------------------
// k0: prep.
//   block 0        : build cat-groups (cat, count<=4, batch ids) serially
//   blocks 1..32   : tau sinusoid (bf16)
//   blocks 33..64  : state_h = relu(state @ se_W1 + b1)
//   blocks 65..256 : a_emb = actions @ ae_W1 + b1 -> bf16
// grp layout (ints): [0]=ngroups; per g at 1+6g: cat, cnt, b0, b1, b2, b3
// ---------------------------------------------------------------------------
__global__ __launch_bounds__(256) void k0(
    const float* __restrict__ state, const float* __restrict__ actions,
    const int* __restrict__ tsteps, const int* __restrict__ cat_ids,
    const float* __restrict__ se_W1, const float* __restrict__ se_b1,
    const float* __restrict__ ae_W1, const float* __restrict__ ae_b1,
    int* __restrict__ grp, unsigned short* __restrict__ tau,
    float* __restrict__ h, unsigned short* __restrict__ aemb) {
    int bid = blockIdx.x, tid = threadIdx.x;

    if (bid == 0) {                         // ---- group build (serial, 32 el)
        if (tid == 0) {
            int cats[B_];
            for (int b = 0; b < B_; ++b) cats[b] = cat_ids[b];
            int ng = 0;
            for (int c = 0; c < E_; ++c) {
                int tmp[B_], cnt = 0;
                for (int b = 0; b < B_; ++b)
                    if (cats[b] == c) tmp[cnt++] = b;
                int i = 0;
                while (i < cnt) {
                    int take = cnt - i; if (take > GMAX) take = GMAX;
                    int* G = grp + 1 + ng * 6;
                    G[0] = c; G[1] = take;
                    for (int s = 0; s < GMAX; ++s)
                        G[2 + s] = tmp[i + (s < take ? s : take - 1)];
                    i += take; ++ng;
                }
            }
            grp[0] = ng;
        }
        return;
    }
    if (bid <= B_) {                        // ---- tau
        int b = bid - 1;
        float t = (float)tsteps[b];
        const int half = EMB / 2;
        for (int i = tid; i < half; i += 256) {
            float div = expf((-logf(10000.0f) * (float)i) / (float)half);
            float ang = t * div;
            tau[b * EMB + i]        = f2bf(sinf(ang));
            tau[b * EMB + half + i] = f2bf(cosf(ang));
        }
        return;
    }
    if (bid <= 2 * B_) {                    // ---- state_h
        int b = bid - (B_ + 1);
        int c = cat_ids[b];
        __shared__ float s[SD];
        if (tid < SD) s[tid] = state[b * SD + tid];
        __syncthreads();
        const float* W = se_W1 + (size_t)c * SD * HID;
        float acc[4];
#pragma unroll
        for (int r = 0; r < 4; ++r) acc[r] = se_b1[c * HID + tid + 256 * r];
        for (int k = 0; k < SD; ++k) {
            float sv = s[k];
#pragma unroll
            for (int r = 0; r < 4; ++r)
                acc[r] += sv * W[(size_t)k * HID + tid + 256 * r];
        }
#pragma unroll
        for (int r = 0; r < 4; ++r) {
            float v = acc[r];
            h[b * HID + tid + 256 * r] = v > 0.f ? v : 0.f;
        }
        return;
    }
    {                                       // ---- aemb
        int idx = bid - (2 * B_ + 1);       // 0..191
        int b = idx & 31, chunk = idx >> 5;
        int c = cat_ids[b];
        __shared__ float sa[T_ * AD];
#pragma unroll
        for (int r = 0; r < 4; ++r)
            sa[tid + 256 * r] = actions[b * T_ * AD + tid + 256 * r];
        __syncthreads();
        int n = chunk * 256 + tid;
        const float* W = ae_W1 + (size_t)c * AD * EMB + n;
        float bv = ae_b1[c * EMB + n];
        float acc[T_];
#pragma unroll
        for (int t = 0; t < T_; ++t) acc[t] = bv;
        for (int k = 0; k < AD; ++k) {
            float w = W[(size_t)k * EMB];
#pragma unroll
            for (int t = 0; t < T_; ++t) acc[t] += sa[t * AD + k] * w;
        }
#pragma unroll
        for (int t = 0; t < T_; ++t)
            aemb[((size_t)b * T_ + t) * EMB + n] = f2bf(acc[t]);
    }
}

// ---------------------------------------------------------------------------
// k1: blocks [0,768)   = grouped big GEMM 1 (cat-group g, 64-col chunk):
//       x3[b_s] = swish(concat(a_emb[b_s],tau[b_s]) @ ae_W2[c] + ae_b2[c])
//     blocks [768,960) = grouped state_feat: out[b_s,0,:] = h[b_s]@se_W2+b2
// Weights streamed ONCE per group; up to 4 batches computed from the same
// registers. 4-wave K-split + per-batch LDS reduce.
// ---------------------------------------------------------------------------
__global__ __launch_bounds__(256, 2) void k1(
    const int* __restrict__ grp, const unsigned short* __restrict__ aemb,
    const unsigned short* __restrict__ tau,
    const float* __restrict__ ae_W2, const float* __restrict__ ae_b2,
    const float* __restrict__ h, const float* __restrict__ se_W2,
    const float* __restrict__ se_b2,
    unsigned short* __restrict__ x3, float* __restrict__ out) {
    __shared__ float lds[4][32][64];        // 32 KB
    int bid = blockIdx.x, tid = threadIdx.x;
    int wv = tid >> 6, lane = tid & 63;
    int ng = grp[0];

    if (bid < 24 * B_) {                    // ---- grouped big1
        int g = bid / 24, chunk = bid % 24;
        if (g >= ng) return;
        const int* G = grp + 1 + g * 6;
        int c = G[0], cnt = G[1];
        int b0 = G[2], b1 = G[3], b2i = G[4], b3 = G[5];
        int bs[GMAX] = {b0, b1, b2i, b3};

        int cq = lane & 15, kg = lane >> 4;
        int ncol = chunk * 64 + 4 * cq;
        const float* Wb = ae_W2 + (size_t)c * K2 * EMB + ncol;

        f32x4 acc[GMAX][2][4];
#pragma unroll
        for (int s = 0; s < GMAX; ++s)
#pragma unroll
            for (int rf = 0; rf < 2; ++rf)
#pragma unroll
                for (int q = 0; q < 4; ++q) acc[s][rf][q] = (f32x4){0.f, 0.f, 0.f, 0.f};

        int kbeg = wv * 768;
        if (wv < 2) {                       // a_emb region (k 0..1535)
            for (int kk = 0; kk < 768; kk += 32) {
                int kb = kbeg + kk + kg * 8;
                f32x4 w[8];
#pragma unroll
                for (int j = 0; j < 8; ++j)
                    w[j] = *(const f32x4*)(Wb + (size_t)(kb + j) * EMB);
                bf16x8 bq[4];
#pragma unroll
                for (int q = 0; q < 4; ++q)
#pragma unroll
                    for (int j = 0; j < 8; ++j) bq[q][j] = (short)f2bf(w[j][q]);
#pragma unroll
                for (int s = 0; s < GMAX; ++s) {
                    if (s < cnt) {
                        const unsigned short* A0 = aemb + (size_t)bs[s] * T_ * EMB;
                        bf16x8 a0 = *(const bf16x8*)(A0 + (size_t)cq * EMB + kb);
                        bf16x8 a1 = *(const bf16x8*)(A0 + (size_t)(cq + 16) * EMB + kb);
#pragma unroll
                        for (int q = 0; q < 4; ++q) {
                            acc[s][0][q] = __builtin_amdgcn_mfma_f32_16x16x32_bf16(a0, bq[q], acc[s][0][q], 0, 0, 0);
                            acc[s][1][q] = __builtin_amdgcn_mfma_f32_16x16x32_bf16(a1, bq[q], acc[s][1][q], 0, 0, 0);
                        }
                    }
                }
            }
        } else {                            // tau region (k 1536..3071)
            for (int kk = 0; kk < 768; kk += 32) {
                int kb = kbeg + kk + kg * 8;
                f32x4 w[8];
#pragma unroll
                for (int j = 0; j < 8; ++j)
                    w[j] = *(const f32x4*)(Wb + (size_t)(kb + j) * EMB);
                bf16x8 bq[4];
#pragma unroll
                for (int q = 0; q < 4; ++q)
#pragma unroll
                    for (int j = 0; j < 8; ++j) bq[q][j] = (short)f2bf(w[j][q]);
#pragma unroll
                for (int s = 0; s < GMAX; ++s) {
                    if (s < cnt) {
                        bf16x8 a = *(const bf16x8*)(tau + (size_t)bs[s] * EMB + (kb - EMB));
#pragma unroll
                        for (int q = 0; q < 4; ++q) {
                            acc[s][0][q] = __builtin_amdgcn_mfma_f32_16x16x32_bf16(a, bq[q], acc[s][0][q], 0, 0, 0);
                            acc[s][1][q] = __builtin_amdgcn_mfma_f32_16x16x32_bf16(a, bq[q], acc[s][1][q], 0, 0, 0);
                        }
                    }
                }
            }
        }
        // per-batch reduce + swish + bf16 store (cnt is block-uniform)
#pragma unroll
        for (int s = 0; s < GMAX; ++s) {
            if (s < cnt) {
                __syncthreads();
#pragma unroll
                for (int rf = 0; rf < 2; ++rf)
#pragma unroll
                    for (int r = 0; r < 4; ++r) {
                        int row = kg * 4 + r + 16 * rf;
                        f32x4 v;
#pragma unroll
                        for (int q = 0; q < 4; ++q) v[q] = acc[s][rf][q][r];
                        *(f32x4*)&lds[wv][row][4 * cq] = v;
                    }
                __syncthreads();
                int row = tid >> 3, c0 = (tid & 7) * 8;
                int gcol = chunk * 64 + c0;
                s16x8 o;
#pragma unroll
                for (int j = 0; j < 8; ++j) {
                    float y = lds[0][row][c0 + j] + lds[1][row][c0 + j]
                            + lds[2][row][c0 + j] + lds[3][row][c0 + j]
                            + ae_b2[c * EMB + gcol + j];
                    o[j] = (short)f2bf(swishf(y));
                }
                *(s16x8*)(x3 + ((size_t)bs[s] * T_ + row) * EMB + gcol) = o;
            }
        }
        return;
    }

    {                                       // ---- grouped state_feat
        int idx = bid - 24 * B_;
        int g = idx / 6, chunk = idx % 6;
        if (g >= ng) return;
        const int* G = grp + 1 + g * 6;
        int c = G[0], cnt = G[1];
        int bs[GMAX] = {G[2], G[3], G[4], G[5]};

        int n = chunk * 256 + 4 * lane;
        const float* W = se_W2 + (size_t)c * HID * EMB + n;
        const float* hb[GMAX];
#pragma unroll
        for (int s = 0; s < GMAX; ++s) hb[s] = h + (size_t)bs[s] * HID;

        f32x4 acc[GMAX];
#pragma unroll
        for (int s = 0; s < GMAX; ++s) acc[s] = (f32x4){0.f, 0.f, 0.f, 0.f};
        int ke = 256 * wv + 256;
#pragma unroll 8
        for (int k = 256 * wv; k < ke; ++k) {
            f32x4 wvv = *(const f32x4*)(W + (size_t)k * EMB);
#pragma unroll
            for (int s = 0; s < GMAX; ++s)
                if (s < cnt) acc[s] += hb[s][k] * wvv;
        }
        // lds_sf[w][s][256 floats]
        float* l = (float*)lds;
#pragma unroll
        for (int s = 0; s < GMAX; ++s)
            if (s < cnt) *(f32x4*)&l[((wv * GMAX + s) * 64 + lane) * 4] = acc[s];
        __syncthreads();
        int s = tid >> 6;                   // 0..3
        if (s < cnt) {
            f32x4 sum = *(f32x4*)&l[((0 * GMAX + s) * 64 + lane) * 4];
#pragma unroll
            for (int w = 1; w < 4; ++w)
                sum += *(f32x4*)&l[((w * GMAX + s) * 64 + lane) * 4];
            sum += *(const f32x4*)(se_b2 + (size_t)c * EMB + chunk * 256 + 4 * lane);
            *(f32x4*)(out + ((size_t)bs[s] * 33) * EMB + chunk * 256 + 4 * lane) = sum;
        }
    }
}

// ---------------------------------------------------------------------------
// k2: grouped big GEMM 2: out[b_s,1+t,:] = x3[b_s] @ ae_W3[c] + ae_b3[c]
// ---------------------------------------------------------------------------
__global__ __launch_bounds__(256, 2) void k2(
    const int* __restrict__ grp, const unsigned short* __restrict__ x3,
    const float* __restrict__ ae_W3, const float* __restrict__ ae_b3,
    float* __restrict__ out) {
    __shared__ float lds[4][32][64];
    int bid = blockIdx.x, tid = threadIdx.x;
    int wv = tid >> 6, lane = tid & 63;
    int ng = grp[0];
    int g = bid / 24, chunk = bid % 24;
    if (g >= ng) return;
    const int* G = grp + 1 + g * 6;
    int c = G[0], cnt = G[1];
    int bs[GMAX] = {G[2], G[3], G[4], G[5]};

    int cq = lane & 15, kg = lane >> 4;
    int ncol = chunk * 64 + 4 * cq;
    const float* Wb = ae_W3 + (size_t)c * EMB * EMB + ncol;
    const unsigned short* A0s[GMAX];
#pragma unroll
    for (int s = 0; s < GMAX; ++s) A0s[s] = x3 + (size_t)bs[s] * T_ * EMB;

    f32x4 acc[GMAX][2][4];
#pragma unroll
    for (int s = 0; s < GMAX; ++s)
#pragma unroll
        for (int rf = 0; rf < 2; ++rf)
#pragma unroll
            for (int q = 0; q < 4; ++q) acc[s][rf][q] = (f32x4){0.f, 0.f, 0.f, 0.f};

    int kbeg = wv * 384;
    for (int kk = 0; kk < 384; kk += 32) {
        int kb = kbeg + kk + kg * 8;
        f32x4 w[8];
#pragma unroll
        for (int j = 0; j < 8; ++j)
            w[j] = *(const f32x4*)(Wb + (size_t)(kb + j) * EMB);
        bf16x8 bq[4];
#pragma unroll
        for (int q = 0; q < 4; ++q)
#pragma unroll
            for (int j = 0; j < 8; ++j) bq[q][j] = (short)f2bf(w[j][q]);
#pragma unroll
        for (int s = 0; s < GMAX; ++s) {
            if (s < cnt) {
                bf16x8 a0 = *(const bf16x8*)(A0s[s] + (size_t)cq * EMB + kb);
                bf16x8 a1 = *(const bf16x8*)(A0s[s] + (size_t)(cq + 16) * EMB + kb);
#pragma unroll
                for (int q = 0; q < 4; ++q) {
                    acc[s][0][q] = __builtin_amdgcn_mfma_f32_16x16x32_bf16(a0, bq[q], acc[s][0][q], 0, 0, 0);
                    acc[s][1][q] = __builtin_amdgcn_mfma_f32_16x16x32_bf16(a1, bq[q], acc[s][1][q], 0, 0, 0);
                }
            }
        }
    }
#pragma unroll
    for (int s = 0; s < GMAX; ++s) {
        if (s < cnt) {
            __syncthreads();
#pragma unroll
            for (int rf = 0; rf < 2; ++rf)
#pragma unroll
                for (int r = 0; r < 4; ++r) {
                    int row = kg * 4 + r + 16 * rf;
                    f32x4 v;
#pragma unroll
                    for (int q = 0; q < 4; ++q) v[q] = acc[s][rf][q][r];
                    *(f32x4*)&lds[wv][row][4 * cq] = v;
                }
            __syncthreads();
            int row = tid >> 3, c0 = (tid & 7) * 8;
            int gcol = chunk * 64 + c0;
            f32x4 o0, o1;
#pragma unroll
            for (int j = 0; j < 4; ++j) {
                o0[j] = lds[0][row][c0 + j] + lds[1][row][c0 + j]
                      + lds[2][row][c0 + j] + lds[3][row][c0 + j]
                      + ae_b3[c * EMB + gcol + j];
                o1[j] = lds[0][row][c0 + 4 + j] + lds[1][row][c0 + 4 + j]
                      + lds[2][row][c0 + 4 + j] + lds[3][row][c0 + 4 + j]
                      + ae_b3[c * EMB + gcol + 4 + j];
            }
            float* orow = out + ((size_t)bs[s] * 33 + 1 + row) * EMB + gcol;
            *(f32x4*)orow = o0;
            *(f32x4*)(orow + 4) = o1;
        }
    }
}

// ---------------------------------------------------------------------------
// workspace layout (bytes):
//   0      : grp     int[256]           (1024; written by k0 each call)
//   1024   : tau     bf16[32][1536]     (98304)
//   99328  : h       f32 [32][1024]     (131072)
//   230400 : a_emb   bf16[32][32][1536] (3145728)
//   3376128: x3      bf16[32][32][1536] (3145728)
//   total  : 6521856
// ---------------------------------------------------------------------------
extern "C" void kernel_launch(void* const* d_in, const int* in_sizes, int n_in,
                              void* d_out, int out_size, void* d_ws, size_t ws_size,
                              hipStream_t stream) {
    const float* state   = (const float*)d_in[0];
    const float* actions = (const float*)d_in[1];
    const int*   tsteps  = (const int*)d_in[2];
    const int*   cat_ids = (const int*)d_in[3];
    const float* se_W1 = (const float*)d_in[4];
    const float* se_b1 = (const float*)d_in[5];
    const float* se_W2 = (const float*)d_in[6];
    const float* se_b2 = (const float*)d_in[7];
    const float* ae_W1 = (const float*)d_in[8];
    const float* ae_b1 = (const float*)d_in[9];
    const float* ae_W2 = (const float*)d_in[10];
    const float* ae_b2 = (const float*)d_in[11];
    const float* ae_W3 = (const float*)d_in[12];
    const float* ae_b3 = (const float*)d_in[13];
    float* out = (float*)d_out;

    char* ws = (char*)d_ws;
    int*            grp  = (int*)(ws + 0);
    unsigned short* tau  = (unsigned short*)(ws + 1024);
    float*          h    = (float*)(ws + 99328);
    unsigned short* aemb = (unsigned short*)(ws + 230400);
    unsigned short* x3   = (unsigned short*)(ws + 3376128);

    k0<<<1 + 2 * B_ + (EMB / 256) * B_, 256, 0, stream>>>(
        state, actions, tsteps, cat_ids, se_W1, se_b1, ae_W1, ae_b1,
        grp, tau, h, aemb);
    k1<<<24 * B_ + 6 * B_, 256, 0, stream>>>(
        grp, aemb, tau, ae_W2, ae_b2, h, se_W2, se_b2, x3, out);
    k2<<<24 * B_, 256, 0, stream>>>(grp, x3, ae_W3, ae_b3, out);
}

// Round 7
// 361.141 us; speedup vs baseline: 1.4205x; 1.4205x over previous
//
#include <hip/hip_runtime.h>
#include <hip/hip_bf16.h>

#define B_   32
#define T_   32
#define E_   32
#define SD   64
#define AD   32
#define HID  1024
#define EMB  1536
#define K2   3072   // 2*EMB
#define GMAX 4      // batches per cat-group (padded with duplicates)
#define NS1  (K2 / 64)    // 48 slabs for big1
#define NS2  (EMB / 64)   // 24 slabs for big2

typedef __attribute__((ext_vector_type(8))) short  bf16x8;
typedef __attribute__((ext_vector_type(4))) short  s16x4;
typedef __attribute__((ext_vector_type(4))) float  f32x4;
typedef __attribute__((ext_vector_type(4))) unsigned int u32x4;

// round-to-nearest-even f32 -> bf16 bits (scalar path)
__device__ __forceinline__ unsigned short f2bf(float f) {
    unsigned u = __builtin_bit_cast(unsigned, f);
    u = u + 0x7fffu + ((u >> 16) & 1u);
    return (unsigned short)(u >> 16);
}

__device__ __forceinline__ float swishf(float y) {
    return y / (1.f + expf(-y));
}

// packed f32x2 -> bf16x2 (RNE), single HW instruction
__device__ __forceinline__ unsigned cvtpk(float lo, float hi) {
    unsigned r;
    asm("v_cvt_pk_bf16_f32 %0, %1, %2" : "=v"(r) : "v"(lo), "v"(hi));
    return r;
}

// async 16B/lane global->LDS copy (dest = uniform base + lane*16, linear)
__device__ __forceinline__ void cp16(const float* g, float* l) {
    __builtin_amdgcn_global_load_lds(
        (const __attribute__((address_space(1))) unsigned int*)g,
        (__attribute__((address_space(3))) unsigned int*)l, 16, 0, 0);
}

// ---------------------------------------------------------------------------
// k0: prep.
//   block 0        : build cat-groups (cat, b0..b3 padded w/ duplicates)
//   blocks 1..32   : tau sinusoid (bf16)
//   blocks 33..64  : state_h = relu(state @ se_W1 + b1)
//   blocks 65..256 : a_emb = actions @ ae_W1 + b1 -> bf16
// grp layout (ints): [0]=ngroups; per g at 1+6g: cat, cnt, b0, b1, b2, b3
// ---------------------------------------------------------------------------
__global__ __launch_bounds__(256) void k0(
    const float* __restrict__ state, const float* __restrict__ actions,
    const int* __restrict__ tsteps, const int* __restrict__ cat_ids,
    const float* __restrict__ se_W1, const float* __restrict__ se_b1,
    const float* __restrict__ ae_W1, const float* __restrict__ ae_b1,
    int* __restrict__ grp, unsigned short* __restrict__ tau,
    float* __restrict__ h, unsigned short* __restrict__ aemb) {
    int bid = blockIdx.x, tid = threadIdx.x;

    if (bid == 0) {                         // ---- group build (serial, tiny)
        if (tid == 0) {
            int cats[B_];
            for (int b = 0; b < B_; ++b) cats[b] = cat_ids[b];
            int ng = 0;
            for (int c = 0; c < E_; ++c) {
                int tmp[B_], cnt = 0;
                for (int b = 0; b < B_; ++b)
                    if (cats[b] == c) tmp[cnt++] = b;
                int i = 0;
                while (i < cnt) {
                    int take = cnt - i; if (take > GMAX) take = GMAX;
                    int* G = grp + 1 + ng * 6;
                    G[0] = c; G[1] = take;
                    for (int s = 0; s < GMAX; ++s)
                        G[2 + s] = tmp[i + (s < take ? s : take - 1)];
                    i += take; ++ng;
                }
            }
            grp[0] = ng;
        }
        return;
    }
    if (bid <= B_) {                        // ---- tau
        int b = bid - 1;
        float t = (float)tsteps[b];
        const int half = EMB / 2;
        for (int i = tid; i < half; i += 256) {
            float div = expf((-logf(10000.0f) * (float)i) / (float)half);
            float ang = t * div;
            tau[b * EMB + i]        = f2bf(sinf(ang));
            tau[b * EMB + half + i] = f2bf(cosf(ang));
        }
        return;
    }
    if (bid <= 2 * B_) {                    // ---- state_h
        int b = bid - (B_ + 1);
        int c = cat_ids[b];
        __shared__ float s[SD];
        if (tid < SD) s[tid] = state[b * SD + tid];
        __syncthreads();
        const float* W = se_W1 + (size_t)c * SD * HID;
        float acc[4];
#pragma unroll
        for (int r = 0; r < 4; ++r) acc[r] = se_b1[c * HID + tid + 256 * r];
        for (int k = 0; k < SD; ++k) {
            float sv = s[k];
#pragma unroll
            for (int r = 0; r < 4; ++r)
                acc[r] += sv * W[(size_t)k * HID + tid + 256 * r];
        }
#pragma unroll
        for (int r = 0; r < 4; ++r) {
            float v = acc[r];
            h[b * HID + tid + 256 * r] = v > 0.f ? v : 0.f;
        }
        return;
    }
    {                                       // ---- aemb
        int idx = bid - (2 * B_ + 1);       // 0..191
        int b = idx & 31, chunk = idx >> 5;
        int c = cat_ids[b];
        __shared__ float sa[T_ * AD];
#pragma unroll
        for (int r = 0; r < 4; ++r)
            sa[tid + 256 * r] = actions[b * T_ * AD + tid + 256 * r];
        __syncthreads();
        int n = chunk * 256 + tid;
        const float* W = ae_W1 + (size_t)c * AD * EMB + n;
        float bv = ae_b1[c * EMB + n];
        float acc[T_];
#pragma unroll
        for (int t = 0; t < T_; ++t) acc[t] = bv;
        for (int k = 0; k < AD; ++k) {
            float w = W[(size_t)k * EMB];
#pragma unroll
            for (int t = 0; t < T_; ++t) acc[t] += sa[t * AD + k] * w;
        }
#pragma unroll
        for (int t = 0; t < T_; ++t)
            aemb[((size_t)b * T_ + t) * EMB + n] = f2bf(acc[t]);
    }
}

// ---------------------------------------------------------------------------
// k1: blocks [0,768)   = grouped big1: x3[b_w] = swish(concat(a_emb,tau)@ae_W2+b2)
//     blocks [768,960) = grouped state_feat
// big1 structure: block = (group, 64-col chunk). W slab (64K x 64col f32,
// 16KB) staged to LDS via async global_load_lds, double-buffered. Wave w
// computes batch G[2+w] over the FULL K range (acc[2][4] only). ds_read_b128
// fragment reads are bank-balanced (8 lanes/16B-slot-quad = 1KB/128B floor).
// ---------------------------------------------------------------------------
__global__ __launch_bounds__(256) void k1(
    const int* __restrict__ grp,
    const unsigned short* __restrict__ aemb, const unsigned short* __restrict__ tau,
    const float* __restrict__ ae_W2, const float* __restrict__ ae_b2,
    const float* __restrict__ h, const float* __restrict__ se_W2,
    const float* __restrict__ se_b2,
    unsigned short* __restrict__ x3, float* __restrict__ out) {
    __shared__ float lds[2][64][64];        // 32 KB (sf part reuses 16 KB)
    int bid = blockIdx.x, tid = threadIdx.x;
    int wv = tid >> 6, lane = tid & 63;
    int ng = grp[0];

    if (bid < 24 * B_) {                    // ---- grouped big1
        int g = bid / 24, chunk = bid % 24;
        if (g >= ng) return;
        const int* G = grp + 1 + g * 6;
        int c = G[0];
        int b = G[2 + wv];                  // this wave's batch (padded)
        int cq = lane & 15, kg = lane >> 4;
        int ncol = chunk * 64 + 4 * cq;
        const float* Wb = ae_W2 + (size_t)c * K2 * EMB + chunk * 64;
        const unsigned short* A0 = aemb + (size_t)b * T_ * EMB;
        const unsigned short* TA = tau + (size_t)b * EMB;
        int srow = lane >> 4;               // staging row-within-quad
        int scol = (lane & 15) * 4;         // staging f32 col offset

        f32x4 acc[2][4];
#pragma unroll
        for (int rf = 0; rf < 2; ++rf)
#pragma unroll
            for (int q = 0; q < 4; ++q) acc[rf][q] = (f32x4){0.f, 0.f, 0.f, 0.f};

        // prologue: stage slab 0
#pragma unroll
        for (int i = 0; i < 4; ++i) {
            int r = wv * 16 + i * 4;
            cp16(Wb + (size_t)(r + srow) * EMB + scol, &lds[0][r][0]);
        }

        for (int s = 0; s < NS1; ++s) {
            __syncthreads();                // slab s staged; buf s^1 free
            int cur = s & 1;
            if (s + 1 < NS1) {              // issue next-slab stage (async)
#pragma unroll
                for (int i = 0; i < 4; ++i) {
                    int r = wv * 16 + i * 4;
                    cp16(Wb + (size_t)((s + 1) * 64 + r + srow) * EMB + scol,
                         &lds[cur ^ 1][r][0]);
                }
            }
            const float* Wl = &lds[cur][0][0];
#pragma unroll
            for (int ks = 0; ks < 2; ++ks) {
                f32x4 w[8];
#pragma unroll
                for (int j = 0; j < 8; ++j)
                    w[j] = *(const f32x4*)(Wl + (ks * 32 + kg * 8 + j) * 64 + 4 * cq);
                bf16x8 bq[4];
#pragma unroll
                for (int q = 0; q < 4; ++q) {
                    u32x4 u;
                    u[0] = cvtpk(w[0][q], w[1][q]);
                    u[1] = cvtpk(w[2][q], w[3][q]);
                    u[2] = cvtpk(w[4][q], w[5][q]);
                    u[3] = cvtpk(w[6][q], w[7][q]);
                    bq[q] = __builtin_bit_cast(bf16x8, u);
                }
                int kbase = s * 64 + ks * 32 + kg * 8;
                if (s < NS1 / 2) {          // a_emb region (k 0..1535)
                    bf16x8 a0 = *(const bf16x8*)(A0 + (size_t)cq * EMB + kbase);
                    bf16x8 a1 = *(const bf16x8*)(A0 + (size_t)(cq + 16) * EMB + kbase);
#pragma unroll
                    for (int q = 0; q < 4; ++q) {
                        acc[0][q] = __builtin_amdgcn_mfma_f32_16x16x32_bf16(a0, bq[q], acc[0][q], 0, 0, 0);
                        acc[1][q] = __builtin_amdgcn_mfma_f32_16x16x32_bf16(a1, bq[q], acc[1][q], 0, 0, 0);
                    }
                } else {                    // tau region (k 1536..3071)
                    bf16x8 a = *(const bf16x8*)(TA + (kbase - EMB));
#pragma unroll
                    for (int q = 0; q < 4; ++q) {
                        acc[0][q] = __builtin_amdgcn_mfma_f32_16x16x32_bf16(a, bq[q], acc[0][q], 0, 0, 0);
                        acc[1][q] = __builtin_amdgcn_mfma_f32_16x16x32_bf16(a, bq[q], acc[1][q], 0, 0, 0);
                    }
                }
            }
        }
        // per-wave epilogue (no LDS): C/D row=(lane>>4)*4+reg+16*rf, col=4cq+q
        f32x4 bias = *(const f32x4*)(ae_b2 + (size_t)c * EMB + ncol);
#pragma unroll
        for (int rf = 0; rf < 2; ++rf)
#pragma unroll
            for (int r = 0; r < 4; ++r) {
                int row = kg * 4 + r + 16 * rf;
                s16x4 o;
#pragma unroll
                for (int q = 0; q < 4; ++q)
                    o[q] = (short)f2bf(swishf(acc[rf][q][r] + bias[q]));
                *(s16x4*)(x3 + ((size_t)b * T_ + row) * EMB + ncol) = o;
            }
        return;
    }

    {                                       // ---- grouped state_feat
        int idx = bid - 24 * B_;
        int g = idx / 6, chunk = idx % 6;
        if (g >= ng) return;
        const int* G = grp + 1 + g * 6;
        int c = G[0];
        int n = chunk * 256 + 4 * lane;
        const float* W = se_W2 + (size_t)c * HID * EMB + n;
        const float* h0 = h + (size_t)G[2] * HID;
        const float* h1 = h + (size_t)G[3] * HID;
        const float* h2 = h + (size_t)G[4] * HID;
        const float* h3 = h + (size_t)G[5] * HID;
        f32x4 a0 = {0.f,0.f,0.f,0.f}, a1 = a0, a2 = a0, a3 = a0;
        int kb = 256 * wv;
#pragma unroll 8
        for (int k = kb; k < kb + 256; ++k) {
            f32x4 wvv = *(const f32x4*)(W + (size_t)k * EMB);
            a0 += h0[k] * wvv; a1 += h1[k] * wvv;
            a2 += h2[k] * wvv; a3 += h3[k] * wvv;
        }
        float* l = (float*)lds;
        *(f32x4*)&l[((wv * 4 + 0) * 64 + lane) * 4] = a0;
        *(f32x4*)&l[((wv * 4 + 1) * 64 + lane) * 4] = a1;
        *(f32x4*)&l[((wv * 4 + 2) * 64 + lane) * 4] = a2;
        *(f32x4*)&l[((wv * 4 + 3) * 64 + lane) * 4] = a3;
        __syncthreads();
        int s = tid >> 6;                   // wave -> batch slot
        f32x4 sum = *(f32x4*)&l[((0 * 4 + s) * 64 + lane) * 4];
#pragma unroll
        for (int w = 1; w < 4; ++w)
            sum += *(f32x4*)&l[((w * 4 + s) * 64 + lane) * 4];
        sum += *(const f32x4*)(se_b2 + (size_t)c * EMB + chunk * 256 + 4 * lane);
        *(f32x4*)(out + ((size_t)G[2 + s] * 33) * EMB + chunk * 256 + 4 * lane) = sum;
    }
}

// ---------------------------------------------------------------------------
// k2: grouped big2: out[b_w,1+t,:] = x3[b_w] @ ae_W3[c] + ae_b3[c]
// same LDS-staged structure, 24 slabs, f32 epilogue.
// ---------------------------------------------------------------------------
__global__ __launch_bounds__(256) void k2(
    const int* __restrict__ grp, const unsigned short* __restrict__ x3,
    const float* __restrict__ ae_W3, const float* __restrict__ ae_b3,
    float* __restrict__ out) {
    __shared__ float lds[2][64][64];
    int bid = blockIdx.x, tid = threadIdx.x;
    int wv = tid >> 6, lane = tid & 63;
    int ng = grp[0];
    int g = bid / 24, chunk = bid % 24;
    if (g >= ng) return;
    const int* G = grp + 1 + g * 6;
    int c = G[0];
    int b = G[2 + wv];
    int cq = lane & 15, kg = lane >> 4;
    int ncol = chunk * 64 + 4 * cq;
    const float* Wb = ae_W3 + (size_t)c * EMB * EMB + chunk * 64;
    const unsigned short* A0 = x3 + (size_t)b * T_ * EMB;
    int srow = lane >> 4;
    int scol = (lane & 15) * 4;

    f32x4 acc[2][4];
#pragma unroll
    for (int rf = 0; rf < 2; ++rf)
#pragma unroll
        for (int q = 0; q < 4; ++q) acc[rf][q] = (f32x4){0.f, 0.f, 0.f, 0.f};

#pragma unroll
    for (int i = 0; i < 4; ++i) {
        int r = wv * 16 + i * 4;
        cp16(Wb + (size_t)(r + srow) * EMB + scol, &lds[0][r][0]);
    }

    for (int s = 0; s < NS2; ++s) {
        __syncthreads();
        int cur = s & 1;
        if (s + 1 < NS2) {
#pragma unroll
            for (int i = 0; i < 4; ++i) {
                int r = wv * 16 + i * 4;
                cp16(Wb + (size_t)((s + 1) * 64 + r + srow) * EMB + scol,
                     &lds[cur ^ 1][r][0]);
            }
        }
        const float* Wl = &lds[cur][0][0];
#pragma unroll
        for (int ks = 0; ks < 2; ++ks) {
            f32x4 w[8];
#pragma unroll
            for (int j = 0; j < 8; ++j)
                w[j] = *(const f32x4*)(Wl + (ks * 32 + kg * 8 + j) * 64 + 4 * cq);
            bf16x8 bq[4];
#pragma unroll
            for (int q = 0; q < 4; ++q) {
                u32x4 u;
                u[0] = cvtpk(w[0][q], w[1][q]);
                u[1] = cvtpk(w[2][q], w[3][q]);
                u[2] = cvtpk(w[4][q], w[5][q]);
                u[3] = cvtpk(w[6][q], w[7][q]);
                bq[q] = __builtin_bit_cast(bf16x8, u);
            }
            int kbase = s * 64 + ks * 32 + kg * 8;
            bf16x8 a0 = *(const bf16x8*)(A0 + (size_t)cq * EMB + kbase);
            bf16x8 a1 = *(const bf16x8*)(A0 + (size_t)(cq + 16) * EMB + kbase);
#pragma unroll
            for (int q = 0; q < 4; ++q) {
                acc[0][q] = __builtin_amdgcn_mfma_f32_16x16x32_bf16(a0, bq[q], acc[0][q], 0, 0, 0);
                acc[1][q] = __builtin_amdgcn_mfma_f32_16x16x32_bf16(a1, bq[q], acc[1][q], 0, 0, 0);
            }
        }
    }
    f32x4 bias = *(const f32x4*)(ae_b3 + (size_t)c * EMB + ncol);
#pragma unroll
    for (int rf = 0; rf < 2; ++rf)
#pragma unroll
        for (int r = 0; r < 4; ++r) {
            int row = kg * 4 + r + 16 * rf;
            f32x4 ov;
#pragma unroll
            for (int q = 0; q < 4; ++q) ov[q] = acc[rf][q][r] + bias[q];
            *(f32x4*)(out + ((size_t)b * 33 + 1 + row) * EMB + ncol) = ov;
        }
}

// ---------------------------------------------------------------------------
// workspace layout (bytes):
//   0      : grp     int[256]           (1024; fully rewritten by k0)
//   1024   : tau     bf16[32][1536]     (98304)
//   99328  : h       f32 [32][1024]     (131072)
//   230400 : a_emb   bf16[32][32][1536] (3145728)
//   3376128: x3      bf16[32][32][1536] (3145728)
//   total  : 6521856
// ---------------------------------------------------------------------------
extern "C" void kernel_launch(void* const* d_in, const int* in_sizes, int n_in,
                              void* d_out, int out_size, void* d_ws, size_t ws_size,
                              hipStream_t stream) {
    const float* state   = (const float*)d_in[0];
    const float* actions = (const float*)d_in[1];
    const int*   tsteps  = (const int*)d_in[2];
    const int*   cat_ids = (const int*)d_in[3];
    const float* se_W1 = (const float*)d_in[4];
    const float* se_b1 = (const float*)d_in[5];
    const float* se_W2 = (const float*)d_in[6];
    const float* se_b2 = (const float*)d_in[7];
    const float* ae_W1 = (const float*)d_in[8];
    const float* ae_b1 = (const float*)d_in[9];
    const float* ae_W2 = (const float*)d_in[10];
    const float* ae_b2 = (const float*)d_in[11];
    const float* ae_W3 = (const float*)d_in[12];
    const float* ae_b3 = (const float*)d_in[13];
    float* out = (float*)d_out;

    char* ws = (char*)d_ws;
    int*            grp  = (int*)(ws + 0);
    unsigned short* tau  = (unsigned short*)(ws + 1024);
    float*          h    = (float*)(ws + 99328);
    unsigned short* aemb = (unsigned short*)(ws + 230400);
    unsigned short* x3   = (unsigned short*)(ws + 3376128);

    k0<<<1 + 2 * B_ + (EMB / 256) * B_, 256, 0, stream>>>(
        state, actions, tsteps, cat_ids, se_W1, se_b1, ae_W1, ae_b1,
        grp, tau, h, aemb);
    k1<<<24 * B_ + 6 * B_, 256, 0, stream>>>(
        grp, aemb, tau, ae_W2, ae_b2, h, se_W2, se_b2, x3, out);
    k2<<<24 * B_, 256, 0, stream>>>(grp, x3, ae_W3, ae_b3, out);
}

// Round 8
// 323.572 us; speedup vs baseline: 1.5854x; 1.1161x over previous
//
#include <hip/hip_runtime.h>
#include <hip/hip_bf16.h>

#define B_   32
#define T_   32
#define E_   32
#define SD   64
#define AD   32
#define HID  1024
#define EMB  1536
#define K2   3072   // 2*EMB
#define GMAX 2      // batches per cat-group (padded by duplicating)

typedef __attribute__((ext_vector_type(8))) short  bf16x8;
typedef __attribute__((ext_vector_type(8))) short  s16x8;
typedef __attribute__((ext_vector_type(4))) short  s16x4;
typedef __attribute__((ext_vector_type(4))) float  f32x4;
typedef __attribute__((ext_vector_type(4))) unsigned int u32x4;

// round-to-nearest-even f32 -> bf16 bits (scalar path)
__device__ __forceinline__ unsigned short f2bf(float f) {
    unsigned u = __builtin_bit_cast(unsigned, f);
    u = u + 0x7fffu + ((u >> 16) & 1u);
    return (unsigned short)(u >> 16);
}

__device__ __forceinline__ float swishf(float y) {
    return y / (1.f + expf(-y));
}

// packed f32x2 -> bf16x2 (RNE), single HW instruction (validated round 7)
__device__ __forceinline__ unsigned cvtpk(float lo, float hi) {
    unsigned r;
    asm("v_cvt_pk_bf16_f32 %0, %1, %2" : "=v"(r) : "v"(lo), "v"(hi));
    return r;
}

// build B-fragment for column residue q from w[8] f32x4
__device__ __forceinline__ bf16x8 mk_bq(const f32x4* w, int q) {
    u32x4 u;
    u[0] = cvtpk(w[0][q], w[1][q]);
    u[1] = cvtpk(w[2][q], w[3][q]);
    u[2] = cvtpk(w[4][q], w[5][q]);
    u[3] = cvtpk(w[6][q], w[7][q]);
    return __builtin_bit_cast(bf16x8, u);
}

// ---------------------------------------------------------------------------
// k0: prep.
//   block 0        : build cat-groups of <=2 batches (padded w/ duplicate)
//   blocks 1..32   : tau sinusoid (bf16)
//   blocks 33..64  : state_h = relu(state @ se_W1 + b1)
//   blocks 65..256 : a_emb = actions @ ae_W1 + b1 -> bf16
// grp layout (ints): [0]=ngroups; per g at 1+4g: cat, b0, b1, pad
// ---------------------------------------------------------------------------
__global__ __launch_bounds__(256) void k0(
    const float* __restrict__ state, const float* __restrict__ actions,
    const int* __restrict__ tsteps, const int* __restrict__ cat_ids,
    const float* __restrict__ se_W1, const float* __restrict__ se_b1,
    const float* __restrict__ ae_W1, const float* __restrict__ ae_b1,
    int* __restrict__ grp, unsigned short* __restrict__ tau,
    float* __restrict__ h, unsigned short* __restrict__ aemb) {
    int bid = blockIdx.x, tid = threadIdx.x;

    if (bid == 0) {                         // ---- group build (serial, tiny)
        if (tid == 0) {
            int cats[B_];
            for (int b = 0; b < B_; ++b) cats[b] = cat_ids[b];
            int ng = 0;
            for (int c = 0; c < E_; ++c) {
                int tmp[B_], cnt = 0;
                for (int b = 0; b < B_; ++b)
                    if (cats[b] == c) tmp[cnt++] = b;
                int i = 0;
                while (i < cnt) {
                    int take = cnt - i; if (take > GMAX) take = GMAX;
                    int* G = grp + 1 + ng * 4;
                    G[0] = c;
                    G[1] = tmp[i];
                    G[2] = tmp[i + take - 1];   // duplicate when take==1
                    i += take; ++ng;
                }
            }
            grp[0] = ng;
        }
        return;
    }
    if (bid <= B_) {                        // ---- tau
        int b = bid - 1;
        float t = (float)tsteps[b];
        const int half = EMB / 2;
        for (int i = tid; i < half; i += 256) {
            float div = expf((-logf(10000.0f) * (float)i) / (float)half);
            float ang = t * div;
            tau[b * EMB + i]        = f2bf(sinf(ang));
            tau[b * EMB + half + i] = f2bf(cosf(ang));
        }
        return;
    }
    if (bid <= 2 * B_) {                    // ---- state_h
        int b = bid - (B_ + 1);
        int c = cat_ids[b];
        __shared__ float s[SD];
        if (tid < SD) s[tid] = state[b * SD + tid];
        __syncthreads();
        const float* W = se_W1 + (size_t)c * SD * HID;
        float acc[4];
#pragma unroll
        for (int r = 0; r < 4; ++r) acc[r] = se_b1[c * HID + tid + 256 * r];
        for (int k = 0; k < SD; ++k) {
            float sv = s[k];
#pragma unroll
            for (int r = 0; r < 4; ++r)
                acc[r] += sv * W[(size_t)k * HID + tid + 256 * r];
        }
#pragma unroll
        for (int r = 0; r < 4; ++r) {
            float v = acc[r];
            h[b * HID + tid + 256 * r] = v > 0.f ? v : 0.f;
        }
        return;
    }
    {                                       // ---- aemb
        int idx = bid - (2 * B_ + 1);       // 0..191
        int b = idx & 31, chunk = idx >> 5;
        int c = cat_ids[b];
        __shared__ float sa[T_ * AD];
#pragma unroll
        for (int r = 0; r < 4; ++r)
            sa[tid + 256 * r] = actions[b * T_ * AD + tid + 256 * r];
        __syncthreads();
        int n = chunk * 256 + tid;
        const float* W = ae_W1 + (size_t)c * AD * EMB + n;
        float bv = ae_b1[c * EMB + n];
        float acc[T_];
#pragma unroll
        for (int t = 0; t < T_; ++t) acc[t] = bv;
        for (int k = 0; k < AD; ++k) {
            float w = W[(size_t)k * EMB];
#pragma unroll
            for (int t = 0; t < T_; ++t) acc[t] += sa[t * AD + k] * w;
        }
#pragma unroll
        for (int t = 0; t < T_; ++t)
            aemb[((size_t)b * T_ + t) * EMB + n] = f2bf(acc[t]);
    }
}

// ---------------------------------------------------------------------------
// k1: blocks [0,768)   = grouped big1 (group g, 64-col chunk):
//       x3[b0],x3[b1] = swish(concat(a_emb,tau) @ ae_W2[c] + ae_b2[c])
//     blocks [768,960) = grouped state_feat
// Round-3 structure (register-direct dwordx4 weight loads, unroll 2, 4-wave
// K-split, LDS reduce) with the 2 same-cat batches STACKED IN M: weight
// fragment loaded once feeds 4 row-fragments (16 MFMAs / 32-K).
// ---------------------------------------------------------------------------
__global__ __launch_bounds__(256) void k1(
    const int* __restrict__ grp,
    const unsigned short* __restrict__ aemb, const unsigned short* __restrict__ tau,
    const float* __restrict__ ae_W2, const float* __restrict__ ae_b2,
    const float* __restrict__ h, const float* __restrict__ se_W2,
    const float* __restrict__ se_b2,
    unsigned short* __restrict__ x3, float* __restrict__ out) {
    __shared__ float lds[4][32][64];        // 32 KB, reused per-batch
    int bid = blockIdx.x, tid = threadIdx.x;
    int wv = tid >> 6, lane = tid & 63;
    int ng = grp[0];

    if (bid < 24 * B_) {                    // ---- grouped big1
        int g = bid / 24, chunk = bid % 24; // group-major: same-cat adjacent
        if (g >= ng) return;
        const int* G = grp + 1 + g * 4;
        int c = G[0], b0 = G[1], b1 = G[2];
        int cq = lane & 15, kg = lane >> 4;
        int ncol = chunk * 64 + 4 * cq;
        const float* Wb = ae_W2 + (size_t)c * K2 * EMB + ncol;
        const unsigned short* A0 = aemb + (size_t)b0 * T_ * EMB;
        const unsigned short* A1 = aemb + (size_t)b1 * T_ * EMB;

        f32x4 acc[4][4];                    // [rowfrag 0..3][q]; rf0,1=b0 rf2,3=b1
#pragma unroll
        for (int rf = 0; rf < 4; ++rf)
#pragma unroll
            for (int q = 0; q < 4; ++q) acc[rf][q] = (f32x4){0.f, 0.f, 0.f, 0.f};

        int kbeg = wv * 768;
        if (wv < 2) {                       // a_emb region (k 0..1535)
#pragma unroll 2
            for (int kk = 0; kk < 768; kk += 32) {
                int kb = kbeg + kk + kg * 8;
                f32x4 w[8];
#pragma unroll
                for (int j = 0; j < 8; ++j)
                    w[j] = *(const f32x4*)(Wb + (size_t)(kb + j) * EMB);
                bf16x8 a0 = *(const bf16x8*)(A0 + (size_t)cq * EMB + kb);
                bf16x8 a1 = *(const bf16x8*)(A0 + (size_t)(cq + 16) * EMB + kb);
                bf16x8 a2 = *(const bf16x8*)(A1 + (size_t)cq * EMB + kb);
                bf16x8 a3 = *(const bf16x8*)(A1 + (size_t)(cq + 16) * EMB + kb);
#pragma unroll
                for (int q = 0; q < 4; ++q) {
                    bf16x8 bq = mk_bq(w, q);
                    acc[0][q] = __builtin_amdgcn_mfma_f32_16x16x32_bf16(a0, bq, acc[0][q], 0, 0, 0);
                    acc[1][q] = __builtin_amdgcn_mfma_f32_16x16x32_bf16(a1, bq, acc[1][q], 0, 0, 0);
                    acc[2][q] = __builtin_amdgcn_mfma_f32_16x16x32_bf16(a2, bq, acc[2][q], 0, 0, 0);
                    acc[3][q] = __builtin_amdgcn_mfma_f32_16x16x32_bf16(a3, bq, acc[3][q], 0, 0, 0);
                }
            }
        } else {                            // tau region (k 1536..3071)
            const unsigned short* TA0 = tau + (size_t)b0 * EMB;
            const unsigned short* TA1 = tau + (size_t)b1 * EMB;
#pragma unroll 2
            for (int kk = 0; kk < 768; kk += 32) {
                int kb = kbeg + kk + kg * 8;
                f32x4 w[8];
#pragma unroll
                for (int j = 0; j < 8; ++j)
                    w[j] = *(const f32x4*)(Wb + (size_t)(kb + j) * EMB);
                bf16x8 t0 = *(const bf16x8*)(TA0 + (kb - EMB));
                bf16x8 t1 = *(const bf16x8*)(TA1 + (kb - EMB));
#pragma unroll
                for (int q = 0; q < 4; ++q) {
                    bf16x8 bq = mk_bq(w, q);
                    acc[0][q] = __builtin_amdgcn_mfma_f32_16x16x32_bf16(t0, bq, acc[0][q], 0, 0, 0);
                    acc[1][q] = __builtin_amdgcn_mfma_f32_16x16x32_bf16(t0, bq, acc[1][q], 0, 0, 0);
                    acc[2][q] = __builtin_amdgcn_mfma_f32_16x16x32_bf16(t1, bq, acc[2][q], 0, 0, 0);
                    acc[3][q] = __builtin_amdgcn_mfma_f32_16x16x32_bf16(t1, bq, acc[3][q], 0, 0, 0);
                }
            }
        }
        // per-batch LDS reduce + swish + bf16 store (b0==b1 dup is benign)
        int bs[2] = {b0, b1};
#pragma unroll
        for (int s = 0; s < 2; ++s) {
            __syncthreads();
#pragma unroll
            for (int rf = 0; rf < 2; ++rf)
#pragma unroll
                for (int r = 0; r < 4; ++r) {
                    int row = kg * 4 + r + 16 * rf;
                    f32x4 v;
#pragma unroll
                    for (int q = 0; q < 4; ++q) v[q] = acc[2 * s + rf][q][r];
                    *(f32x4*)&lds[wv][row][4 * cq] = v;
                }
            __syncthreads();
            int row = tid >> 3, c0 = (tid & 7) * 8;
            int gcol = chunk * 64 + c0;
            s16x8 o;
#pragma unroll
            for (int j = 0; j < 8; ++j) {
                float y = lds[0][row][c0 + j] + lds[1][row][c0 + j]
                        + lds[2][row][c0 + j] + lds[3][row][c0 + j]
                        + ae_b2[c * EMB + gcol + j];
                o[j] = (short)f2bf(swishf(y));
            }
            *(s16x8*)(x3 + ((size_t)bs[s] * T_ + row) * EMB + gcol) = o;
        }
        return;
    }

    {                                       // ---- grouped state_feat
        int idx = bid - 24 * B_;
        int g = idx / 6, chunk = idx % 6;   // group-major
        if (g >= ng) return;
        const int* G = grp + 1 + g * 4;
        int c = G[0];
        int n = chunk * 256 + 4 * lane;
        const float* W = se_W2 + (size_t)c * HID * EMB + n;
        const float* h0 = h + (size_t)G[1] * HID;
        const float* h1 = h + (size_t)G[2] * HID;
        f32x4 a0 = {0.f, 0.f, 0.f, 0.f}, a1 = a0;
        int kb = 256 * wv;
#pragma unroll 8
        for (int k = kb; k < kb + 256; ++k) {
            f32x4 wvv = *(const f32x4*)(W + (size_t)k * EMB);
            a0 += h0[k] * wvv;
            a1 += h1[k] * wvv;
        }
        float* l = (float*)lds;             // [wv][s][64 lanes][4]
        *(f32x4*)&l[((wv * 2 + 0) * 64 + lane) * 4] = a0;
        *(f32x4*)&l[((wv * 2 + 1) * 64 + lane) * 4] = a1;
        __syncthreads();
        if (tid < 128) {                    // wave 0: batch0, wave 1: batch1
            int s = tid >> 6;
            f32x4 sum = *(f32x4*)&l[((0 * 2 + s) * 64 + lane) * 4];
#pragma unroll
            for (int w = 1; w < 4; ++w)
                sum += *(f32x4*)&l[((w * 2 + s) * 64 + lane) * 4];
            sum += *(const f32x4*)(se_b2 + (size_t)c * EMB + chunk * 256 + 4 * lane);
            *(f32x4*)(out + ((size_t)G[1 + s] * 33) * EMB + chunk * 256 + 4 * lane) = sum;
        }
    }
}

// ---------------------------------------------------------------------------
// k2: grouped big2: out[b0/b1, 1+t, :] = x3 @ ae_W3[c] + ae_b3[c]
// same stacked-M register structure, K-split 384/wave.
// ---------------------------------------------------------------------------
__global__ __launch_bounds__(256) void k2(
    const int* __restrict__ grp, const unsigned short* __restrict__ x3,
    const float* __restrict__ ae_W3, const float* __restrict__ ae_b3,
    float* __restrict__ out) {
    __shared__ float lds[4][32][64];
    int bid = blockIdx.x, tid = threadIdx.x;
    int wv = tid >> 6, lane = tid & 63;
    int ng = grp[0];
    int g = bid / 24, chunk = bid % 24;
    if (g >= ng) return;
    const int* G = grp + 1 + g * 4;
    int c = G[0], b0 = G[1], b1 = G[2];
    int cq = lane & 15, kg = lane >> 4;
    int ncol = chunk * 64 + 4 * cq;
    const float* Wb = ae_W3 + (size_t)c * EMB * EMB + ncol;
    const unsigned short* A0 = x3 + (size_t)b0 * T_ * EMB;
    const unsigned short* A1 = x3 + (size_t)b1 * T_ * EMB;

    f32x4 acc[4][4];
#pragma unroll
    for (int rf = 0; rf < 4; ++rf)
#pragma unroll
        for (int q = 0; q < 4; ++q) acc[rf][q] = (f32x4){0.f, 0.f, 0.f, 0.f};

    int kbeg = wv * 384;
#pragma unroll 2
    for (int kk = 0; kk < 384; kk += 32) {
        int kb = kbeg + kk + kg * 8;
        f32x4 w[8];
#pragma unroll
        for (int j = 0; j < 8; ++j)
            w[j] = *(const f32x4*)(Wb + (size_t)(kb + j) * EMB);
        bf16x8 a0 = *(const bf16x8*)(A0 + (size_t)cq * EMB + kb);
        bf16x8 a1 = *(const bf16x8*)(A0 + (size_t)(cq + 16) * EMB + kb);
        bf16x8 a2 = *(const bf16x8*)(A1 + (size_t)cq * EMB + kb);
        bf16x8 a3 = *(const bf16x8*)(A1 + (size_t)(cq + 16) * EMB + kb);
#pragma unroll
        for (int q = 0; q < 4; ++q) {
            bf16x8 bq = mk_bq(w, q);
            acc[0][q] = __builtin_amdgcn_mfma_f32_16x16x32_bf16(a0, bq, acc[0][q], 0, 0, 0);
            acc[1][q] = __builtin_amdgcn_mfma_f32_16x16x32_bf16(a1, bq, acc[1][q], 0, 0, 0);
            acc[2][q] = __builtin_amdgcn_mfma_f32_16x16x32_bf16(a2, bq, acc[2][q], 0, 0, 0);
            acc[3][q] = __builtin_amdgcn_mfma_f32_16x16x32_bf16(a3, bq, acc[3][q], 0, 0, 0);
        }
    }

    int bs[2] = {b0, b1};
#pragma unroll
    for (int s = 0; s < 2; ++s) {
        __syncthreads();
#pragma unroll
        for (int rf = 0; rf < 2; ++rf)
#pragma unroll
            for (int r = 0; r < 4; ++r) {
                int row = kg * 4 + r + 16 * rf;
                f32x4 v;
#pragma unroll
                for (int q = 0; q < 4; ++q) v[q] = acc[2 * s + rf][q][r];
                *(f32x4*)&lds[wv][row][4 * cq] = v;
            }
        __syncthreads();
        int row = tid >> 3, c0 = (tid & 7) * 8;
        int gcol = chunk * 64 + c0;
        f32x4 o0, o1;
#pragma unroll
        for (int j = 0; j < 4; ++j) {
            o0[j] = lds[0][row][c0 + j] + lds[1][row][c0 + j]
                  + lds[2][row][c0 + j] + lds[3][row][c0 + j]
                  + ae_b3[c * EMB + gcol + j];
            o1[j] = lds[0][row][c0 + 4 + j] + lds[1][row][c0 + 4 + j]
                  + lds[2][row][c0 + 4 + j] + lds[3][row][c0 + 4 + j]
                  + ae_b3[c * EMB + gcol + 4 + j];
        }
        float* orow = out + ((size_t)bs[s] * 33 + 1 + row) * EMB + gcol;
        *(f32x4*)orow = o0;
        *(f32x4*)(orow + 4) = o1;
    }
}

// ---------------------------------------------------------------------------
// workspace layout (bytes):
//   0      : grp     int[1+4*32]        (1024; fully rewritten by k0)
//   1024   : tau     bf16[32][1536]     (98304)
//   99328  : h       f32 [32][1024]     (131072)
//   230400 : a_emb   bf16[32][32][1536] (3145728)
//   3376128: x3      bf16[32][32][1536] (3145728)
//   total  : 6521856
// ---------------------------------------------------------------------------
extern "C" void kernel_launch(void* const* d_in, const int* in_sizes, int n_in,
                              void* d_out, int out_size, void* d_ws, size_t ws_size,
                              hipStream_t stream) {
    const float* state   = (const float*)d_in[0];
    const float* actions = (const float*)d_in[1];
    const int*   tsteps  = (const int*)d_in[2];
    const int*   cat_ids = (const int*)d_in[3];
    const float* se_W1 = (const float*)d_in[4];
    const float* se_b1 = (const float*)d_in[5];
    const float* se_W2 = (const float*)d_in[6];
    const float* se_b2 = (const float*)d_in[7];
    const float* ae_W1 = (const float*)d_in[8];
    const float* ae_b1 = (const float*)d_in[9];
    const float* ae_W2 = (const float*)d_in[10];
    const float* ae_b2 = (const float*)d_in[11];
    const float* ae_W3 = (const float*)d_in[12];
    const float* ae_b3 = (const float*)d_in[13];
    float* out = (float*)d_out;

    char* ws = (char*)d_ws;
    int*            grp  = (int*)(ws + 0);
    unsigned short* tau  = (unsigned short*)(ws + 1024);
    float*          h    = (float*)(ws + 99328);
    unsigned short* aemb = (unsigned short*)(ws + 230400);
    unsigned short* x3   = (unsigned short*)(ws + 3376128);

    k0<<<1 + 2 * B_ + (EMB / 256) * B_, 256, 0, stream>>>(
        state, actions, tsteps, cat_ids, se_W1, se_b1, ae_W1, ae_b1,
        grp, tau, h, aemb);
    k1<<<24 * B_ + 6 * B_, 256, 0, stream>>>(
        grp, aemb, tau, ae_W2, ae_b2, h, se_W2, se_b2, x3, out);
    k2<<<24 * B_, 256, 0, stream>>>(grp, x3, ae_W3, ae_b3, out);
}

// Round 11
// 212.510 us; speedup vs baseline: 2.4140x; 1.5226x over previous
//
#include <hip/hip_runtime.h>
#include <hip/hip_bf16.h>

#define B_   32
#define T_   32
#define E_   32
#define SD   64
#define AD   32
#define HID  1024
#define EMB  1536
#define K2   3072   // 2*EMB

typedef __attribute__((ext_vector_type(8))) short  bf16x8;
typedef __attribute__((ext_vector_type(8))) short  s16x8;
typedef __attribute__((ext_vector_type(4))) float  f32x4;

// round-to-nearest-even f32 -> bf16 bits (manual RNE — the validated path;
// v_cvt_pk_bf16_f32 asm is BANNED: implicated in r9/r10 absmax failures)
__device__ __forceinline__ unsigned short f2bf(float f) {
    unsigned u = __builtin_bit_cast(unsigned, f);
    u = u + 0x7fffu + ((u >> 16) & 1u);
    return (unsigned short)(u >> 16);
}

__device__ __forceinline__ float swishf(float y) {
    return y / (1.f + expf(-y));
}

// ---------------------------------------------------------------------------
// k0: fused independent prep work.
//   block 0        : cat-sorted batch order (serial, trivial)
//   blocks 1..32   : tau sinusoid table (bf16) for batch bid-1
//   blocks 33..64  : state encoder layer 1 (relu(state@se_W1+b1)) for bid-33
//   blocks 65..256 : a_emb = actions @ ae_W1 + b1 -> bf16  (192 blocks)
// ---------------------------------------------------------------------------
__global__ __launch_bounds__(256) void k0(
    const float* __restrict__ state, const float* __restrict__ actions,
    const int* __restrict__ tsteps, const int* __restrict__ cat_ids,
    const float* __restrict__ se_W1, const float* __restrict__ se_b1,
    const float* __restrict__ ae_W1, const float* __restrict__ ae_b1,
    int* __restrict__ order, unsigned short* __restrict__ tau,
    float* __restrict__ h, unsigned short* __restrict__ aemb) {
    int bid = blockIdx.x, tid = threadIdx.x;

    if (bid == 0) {                         // ---- order sort
        __shared__ int cats[B_];
        if (tid < B_) cats[tid] = cat_ids[tid];
        __syncthreads();
        if (tid == 0) {
            int idx = 0;
            for (int c = 0; c < E_; ++c)
                for (int b = 0; b < B_; ++b)
                    if (cats[b] == c) order[idx++] = b;
        }
        return;
    }
    if (bid <= B_) {                        // ---- tau
        int b = bid - 1;
        float t = (float)tsteps[b];
        const int half = EMB / 2;
        for (int i = tid; i < half; i += 256) {
            float div = expf((-logf(10000.0f) * (float)i) / (float)half);
            float ang = t * div;
            tau[b * EMB + i]        = f2bf(sinf(ang));
            tau[b * EMB + half + i] = f2bf(cosf(ang));
        }
        return;
    }
    if (bid <= 2 * B_) {                    // ---- state_h
        int b = bid - (B_ + 1);
        int c = cat_ids[b];
        __shared__ float s[SD];
        if (tid < SD) s[tid] = state[b * SD + tid];
        __syncthreads();
        const float* W = se_W1 + (size_t)c * SD * HID;
        float acc[4];
#pragma unroll
        for (int r = 0; r < 4; ++r) acc[r] = se_b1[c * HID + tid + 256 * r];
        for (int k = 0; k < SD; ++k) {
            float sv = s[k];
#pragma unroll
            for (int r = 0; r < 4; ++r)
                acc[r] += sv * W[(size_t)k * HID + tid + 256 * r];
        }
#pragma unroll
        for (int r = 0; r < 4; ++r) {
            float v = acc[r];
            h[b * HID + tid + 256 * r] = v > 0.f ? v : 0.f;
        }
        return;
    }
    // ---- aemb: (32x32)@(32x1536)
    {
        int idx = bid - (2 * B_ + 1);       // 0..191
        int b = idx & 31, chunk = idx >> 5;
        int c = cat_ids[b];
        __shared__ float sa[T_ * AD];
#pragma unroll
        for (int r = 0; r < 4; ++r)
            sa[tid + 256 * r] = actions[b * T_ * AD + tid + 256 * r];
        __syncthreads();
        int n = chunk * 256 + tid;
        const float* W = ae_W1 + (size_t)c * AD * EMB + n;
        float bv = ae_b1[c * EMB + n];
        float acc[T_];
#pragma unroll
        for (int t = 0; t < T_; ++t) acc[t] = bv;
        for (int k = 0; k < AD; ++k) {
            float w = W[(size_t)k * EMB];
#pragma unroll
            for (int t = 0; t < T_; ++t) acc[t] += sa[t * AD + k] * w;
        }
#pragma unroll
        for (int t = 0; t < T_; ++t)
            aemb[((size_t)b * T_ + t) * EMB + n] = f2bf(acc[t]);
    }
}

// ---------------------------------------------------------------------------
// k1: blocks 0..767  = big GEMM 1 (x3 = swish(concat(a_emb,tau)@ae_W2+b2))
//     blocks 768..959 = state_feat (out row0 = h@se_W2+b2)
// Both: 4-wave K-split + LDS reduce. big1: wave w owns k in [768w,768w+768)
// (waves 0,1 -> a_emb region; waves 2,3 -> tau region). Lane loads
// W[k][4*(lane&15)+q..+3] as dwordx4; 4 MFMAs per (rowhalf,k-step), one per
// column residue q; MFMA col c maps to global col 4c+q.
// ---------------------------------------------------------------------------
__global__ __launch_bounds__(256) void k1(
    const int* __restrict__ order, const int* __restrict__ cat_ids,
    const unsigned short* __restrict__ aemb, const unsigned short* __restrict__ tau,
    const float* __restrict__ ae_W2, const float* __restrict__ ae_b2,
    const float* __restrict__ h, const float* __restrict__ se_W2,
    const float* __restrict__ se_b2,
    unsigned short* __restrict__ x3, float* __restrict__ out) {
    __shared__ float lds[4][32][64];        // 32 KB partial staging
    int bid = blockIdx.x, tid = threadIdx.x;
    int wv = tid >> 6, lane = tid & 63;

    if (bid < (EMB / 64) * B_) {            // ---- big1 (768 blocks)
        int slot = bid & 31, chunk = bid >> 5;
        int b = order[slot];
        int c = cat_ids[b];
        int cq = lane & 15, kg = lane >> 4;
        const float* Wb = ae_W2 + (size_t)c * K2 * EMB + chunk * 64 + 4 * cq;

        f32x4 acc[2][4];
#pragma unroll
        for (int rf = 0; rf < 2; ++rf)
#pragma unroll
            for (int q = 0; q < 4; ++q) acc[rf][q] = (f32x4){0.f, 0.f, 0.f, 0.f};

        int kbeg = wv * 768;
        if (wv < 2) {                       // a_emb region (k 0..1535)
            const unsigned short* A0 = aemb + (size_t)b * T_ * EMB;
#pragma unroll 2
            for (int kk = 0; kk < 768; kk += 32) {
                int kb = kbeg + kk + kg * 8;
                f32x4 w[8];
#pragma unroll
                for (int j = 0; j < 8; ++j)
                    w[j] = *(const f32x4*)(Wb + (size_t)(kb + j) * EMB);
                bf16x8 bq[4];
#pragma unroll
                for (int q = 0; q < 4; ++q) {
#pragma unroll
                    for (int j = 0; j < 8; ++j) bq[q][j] = (short)f2bf(w[j][q]);
                }
                bf16x8 a0 = *(const bf16x8*)(A0 + (size_t)cq * EMB + kb);
                bf16x8 a1 = *(const bf16x8*)(A0 + (size_t)(cq + 16) * EMB + kb);
#pragma unroll
                for (int q = 0; q < 4; ++q) {
                    acc[0][q] = __builtin_amdgcn_mfma_f32_16x16x32_bf16(a0, bq[q], acc[0][q], 0, 0, 0);
                    acc[1][q] = __builtin_amdgcn_mfma_f32_16x16x32_bf16(a1, bq[q], acc[1][q], 0, 0, 0);
                }
            }
        } else {                            // tau region (k 1536..3071)
            const unsigned short* TA = tau + (size_t)b * EMB;
#pragma unroll 2
            for (int kk = 0; kk < 768; kk += 32) {
                int kb = kbeg + kk + kg * 8;
                f32x4 w[8];
#pragma unroll
                for (int j = 0; j < 8; ++j)
                    w[j] = *(const f32x4*)(Wb + (size_t)(kb + j) * EMB);
                bf16x8 bq[4];
#pragma unroll
                for (int q = 0; q < 4; ++q) {
#pragma unroll
                    for (int j = 0; j < 8; ++j) bq[q][j] = (short)f2bf(w[j][q]);
                }
                bf16x8 a = *(const bf16x8*)(TA + (kb - EMB));
#pragma unroll
                for (int q = 0; q < 4; ++q) {
                    acc[0][q] = __builtin_amdgcn_mfma_f32_16x16x32_bf16(a, bq[q], acc[0][q], 0, 0, 0);
                    acc[1][q] = __builtin_amdgcn_mfma_f32_16x16x32_bf16(a, bq[q], acc[1][q], 0, 0, 0);
                }
            }
        }
        // stage partials: C/D layout row=(lane>>4)*4+reg+16*rf, col=4*cq+q
#pragma unroll
        for (int rf = 0; rf < 2; ++rf)
#pragma unroll
            for (int r = 0; r < 4; ++r) {
                int row = kg * 4 + r + 16 * rf;
                f32x4 v;
#pragma unroll
                for (int q = 0; q < 4; ++q) v[q] = acc[rf][q][r];
                *(f32x4*)&lds[wv][row][4 * cq] = v;
            }
        __syncthreads();
        // epilogue: thread -> (row=tid>>3, cols 8*(tid&7)..+7)
        int row = tid >> 3, c0 = (tid & 7) * 8;
        int gcol = chunk * 64 + c0;
        s16x8 o;
#pragma unroll
        for (int j = 0; j < 8; ++j) {
            float y = lds[0][row][c0 + j] + lds[1][row][c0 + j]
                    + lds[2][row][c0 + j] + lds[3][row][c0 + j]
                    + ae_b2[c * EMB + gcol + j];
            o[j] = (short)f2bf(swishf(y));
        }
        *(s16x8*)(x3 + ((size_t)b * T_ + row) * EMB + gcol) = o;
    } else {                                // ---- state_feat (192 blocks)
        int idx = bid - (EMB / 64) * B_;
        int slot = idx & 31, chunk = idx >> 5;
        int b = order[slot];
        int c = cat_ids[b];
        int n = chunk * 256 + 4 * lane;
        const float* W = se_W2 + (size_t)c * HID * EMB + n;
        const float* hb = h + (size_t)b * HID;
        f32x4 acc = {0.f, 0.f, 0.f, 0.f};
        int ke = 256 * wv + 256;
#pragma unroll 16
        for (int k = 256 * wv; k < ke; ++k) {
            f32x4 wvv = *(const f32x4*)(W + (size_t)k * EMB);
            float hk = hb[k];
            acc += hk * wvv;
        }
        float* l = (float*)lds;
        *(f32x4*)&l[(wv * 64 + lane) * 4] = acc;
        __syncthreads();
        if (tid < 64) {
            f32x4 s = *(f32x4*)&l[tid * 4];
#pragma unroll
            for (int w = 1; w < 4; ++w) s += *(f32x4*)&l[(w * 64 + tid) * 4];
            s += *(const f32x4*)(se_b2 + (size_t)c * EMB + chunk * 256 + 4 * tid);
            *(f32x4*)(out + ((size_t)b * 33) * EMB + chunk * 256 + 4 * tid) = s;
        }
    }
}

// ---------------------------------------------------------------------------
// k2: big GEMM 2: out[b,1+t,:] = x3 @ ae_W3[c] + ae_b3[c]
// 4-wave K-split (384 each) + LDS reduce, f32x4 stores.
// ---------------------------------------------------------------------------
__global__ __launch_bounds__(256) void k2(
    const int* __restrict__ order, const int* __restrict__ cat_ids,
    const unsigned short* __restrict__ x3, const float* __restrict__ ae_W3,
    const float* __restrict__ ae_b3, float* __restrict__ out) {
    __shared__ float lds[4][32][64];
    int bid = blockIdx.x, tid = threadIdx.x;
    int wv = tid >> 6, lane = tid & 63;
    int slot = bid & 31, chunk = bid >> 5;
    int b = order[slot];
    int c = cat_ids[b];
    int cq = lane & 15, kg = lane >> 4;
    const float* Wb = ae_W3 + (size_t)c * EMB * EMB + chunk * 64 + 4 * cq;
    const unsigned short* A0 = x3 + (size_t)b * T_ * EMB;

    f32x4 acc[2][4];
#pragma unroll
    for (int rf = 0; rf < 2; ++rf)
#pragma unroll
        for (int q = 0; q < 4; ++q) acc[rf][q] = (f32x4){0.f, 0.f, 0.f, 0.f};

    int kbeg = wv * 384;
#pragma unroll 2
    for (int kk = 0; kk < 384; kk += 32) {
        int kb = kbeg + kk + kg * 8;
        f32x4 w[8];
#pragma unroll
        for (int j = 0; j < 8; ++j)
            w[j] = *(const f32x4*)(Wb + (size_t)(kb + j) * EMB);
        bf16x8 bq[4];
#pragma unroll
        for (int q = 0; q < 4; ++q) {
#pragma unroll
            for (int j = 0; j < 8; ++j) bq[q][j] = (short)f2bf(w[j][q]);
        }
        bf16x8 a0 = *(const bf16x8*)(A0 + (size_t)cq * EMB + kb);
        bf16x8 a1 = *(const bf16x8*)(A0 + (size_t)(cq + 16) * EMB + kb);
#pragma unroll
        for (int q = 0; q < 4; ++q) {
            acc[0][q] = __builtin_amdgcn_mfma_f32_16x16x32_bf16(a0, bq[q], acc[0][q], 0, 0, 0);
            acc[1][q] = __builtin_amdgcn_mfma_f32_16x16x32_bf16(a1, bq[q], acc[1][q], 0, 0, 0);
        }
    }
#pragma unroll
    for (int rf = 0; rf < 2; ++rf)
#pragma unroll
        for (int r = 0; r < 4; ++r) {
            int row = kg * 4 + r + 16 * rf;
            f32x4 v;
#pragma unroll
            for (int q = 0; q < 4; ++q) v[q] = acc[rf][q][r];
            *(f32x4*)&lds[wv][row][4 * cq] = v;
        }
    __syncthreads();
    int row = tid >> 3, c0 = (tid & 7) * 8;
    int gcol = chunk * 64 + c0;
    f32x4 o0, o1;
#pragma unroll
    for (int j = 0; j < 4; ++j) {
        o0[j] = lds[0][row][c0 + j] + lds[1][row][c0 + j]
              + lds[2][row][c0 + j] + lds[3][row][c0 + j]
              + ae_b3[c * EMB + gcol + j];
        o1[j] = lds[0][row][c0 + 4 + j] + lds[1][row][c0 + 4 + j]
              + lds[2][row][c0 + 4 + j] + lds[3][row][c0 + 4 + j]
              + ae_b3[c * EMB + gcol + 4 + j];
    }
    float* orow = out + ((size_t)b * 33 + 1 + row) * EMB + gcol;
    *(f32x4*)orow = o0;
    *(f32x4*)(orow + 4) = o1;
}

// ---------------------------------------------------------------------------
// workspace layout (bytes, 256-aligned):
//   0      : order   int[32]
//   256    : tau     bf16[32][1536]   (98304)
//   98560  : h       f32 [32][1024]   (131072)
//   229632 : a_emb   bf16[32][32][1536] (3145728)
//   3375360: x3      bf16[32][32][1536] (3145728)
//   total  : 6521088
// ---------------------------------------------------------------------------
extern "C" void kernel_launch(void* const* d_in, const int* in_sizes, int n_in,
                              void* d_out, int out_size, void* d_ws, size_t ws_size,
                              hipStream_t stream) {
    const float* state   = (const float*)d_in[0];
    const float* actions = (const float*)d_in[1];
    const int*   tsteps  = (const int*)d_in[2];
    const int*   cat_ids = (const int*)d_in[3];
    const float* se_W1 = (const float*)d_in[4];
    const float* se_b1 = (const float*)d_in[5];
    const float* se_W2 = (const float*)d_in[6];
    const float* se_b2 = (const float*)d_in[7];
    const float* ae_W1 = (const float*)d_in[8];
    const float* ae_b1 = (const float*)d_in[9];
    const float* ae_W2 = (const float*)d_in[10];
    const float* ae_b2 = (const float*)d_in[11];
    const float* ae_W3 = (const float*)d_in[12];
    const float* ae_b3 = (const float*)d_in[13];
    float* out = (float*)d_out;

    char* ws = (char*)d_ws;
    int*            order = (int*)(ws + 0);
    unsigned short* tau   = (unsigned short*)(ws + 256);
    float*          h     = (float*)(ws + 98560);
    unsigned short* aemb  = (unsigned short*)(ws + 229632);
    unsigned short* x3    = (unsigned short*)(ws + 3375360);

    k0<<<1 + 2 * B_ + (EMB / 256) * B_, 256, 0, stream>>>(
        state, actions, tsteps, cat_ids, se_W1, se_b1, ae_W1, ae_b1,
        order, tau, h, aemb);
    k1<<<(EMB / 64) * B_ + (EMB / 256) * B_, 256, 0, stream>>>(
        order, cat_ids, aemb, tau, ae_W2, ae_b2, h, se_W2, se_b2, x3, out);
    k2<<<(EMB / 64) * B_, 256, 0, stream>>>(order, cat_ids, x3, ae_W3, ae_b3, out);
}